// Round 5
// baseline (228.326 us; speedup 1.0000x reference)
//
#include <hip/hip_runtime.h>
#include <math.h>

#define HIDDEN 128
#define HEADS 8
#define HDIM 16
#define NSEQ 512
#define NBATCH 4
#define SROW 10         // sS row stride, [k][h] layout: all phases <=2-way banks
#define NEGINF (-1e30f)

// v += lane-permuted v, all in VALU (DPP) or LDS-pipe-no-conflict (swizzle).
template <int CTRL>
__device__ __forceinline__ float dppadd(float v) {
    int s = __builtin_amdgcn_update_dpp(0, __float_as_int(v), CTRL, 0xF, 0xF, true);
    return v + __int_as_float(s);
}
__device__ __forceinline__ float swzadd_x16(float v) {
    int s = __builtin_amdgcn_ds_swizzle(__float_as_int(v), 0x401F);  // xor lane^16
    return v + __int_as_float(s);
}
#define QUAD_X1 0xB1    // quad_perm [1,0,3,2]
#define QUAD_X2 0x4E    // quad_perm [2,3,0,1]
#define ROW_SHR4 0x114
#define ROW_SHR8 0x118

// ---------------- Kernel 1: fused Q/K/V projection ----------------
__global__ __launch_bounds__(128) void qkv_proj(
    const float* __restrict__ node,
    const float* __restrict__ Wq, const float* __restrict__ bq,
    const float* __restrict__ Wk, const float* __restrict__ bk,
    const float* __restrict__ Wv, const float* __restrict__ bv,
    float* __restrict__ Q, float* __restrict__ K, float* __restrict__ V)
{
    const int ROWS = 8;
    __shared__ float sX[ROWS][HIDDEN];
    const int row0 = blockIdx.x * ROWS;
    const int tid = threadIdx.x;

    const float4* src = (const float4*)(node + row0 * HIDDEN);
    float4* dst = (float4*)(&sX[0][0]);
    #pragma unroll
    for (int i = 0; i < ROWS * HIDDEN / 4 / 128; i++)
        dst[tid + i * 128] = src[tid + i * 128];
    __syncthreads();

    float accQ[ROWS], accK[ROWS], accV[ROWS];
    #pragma unroll
    for (int r = 0; r < ROWS; r++) { accQ[r] = 0.f; accK[r] = 0.f; accV[r] = 0.f; }
    const int c = tid;
    for (int d = 0; d < HIDDEN; d++) {
        const float wq = Wq[d * HIDDEN + c];
        const float wk = Wk[d * HIDDEN + c];
        const float wv = Wv[d * HIDDEN + c];
        #pragma unroll
        for (int r = 0; r < ROWS; r++) {
            const float x = sX[r][d];
            accQ[r] = fmaf(x, wq, accQ[r]);
            accK[r] = fmaf(x, wk, accK[r]);
            accV[r] = fmaf(x, wv, accV[r]);
        }
    }
    const float bqv = bq[c], bkv = bk[c], bvv = bv[c];
    #pragma unroll
    for (int r = 0; r < ROWS; r++) {
        const int off = (row0 + r) * HIDDEN + c;
        Q[off] = accQ[r] + bqv;
        K[off] = accK[r] + bkv;
        V[off] = accV[r] + bvv;
    }
}

// ---------------- Kernel 2: fused attention, barrier-free k-loop ----------------
// sS is [k][h] (stride SROW). Wave w owns score rows with (k&31)>>3 == w in
// BOTH phase A (QK) and phase B (bias+mask RMW) -> no cross-wave deps, no
// __syncthreads (= no vmcnt(0) drain) until softmax.
__global__ __launch_bounds__(256, 4) void attn_fused(
    const float* __restrict__ ef,     // [B][N][N][HIDDEN]
    const int*   __restrict__ mask,   // [B][N][N]
    const float* __restrict__ We,     // [HIDDEN][HEADS]
    const float* __restrict__ be,     // [HEADS]
    const float* __restrict__ Q, const float* __restrict__ K,
    const float* __restrict__ V,
    float* __restrict__ attn)         // [B*N][HIDDEN]
{
    __shared__ float sS[NSEQ * SROW];   // scores -> weights, [k][h]
    __shared__ float sPd[8 * 132];      // PV partials

    const int bq = blockIdx.x;          // b*512 + q
    const int b  = bq >> 9;
    const int tid = threadIdx.x;
    const int wv = tid >> 6;            // wave id 0..3
    const int lane = tid & 63;
    const int c4 = lane & 31;           // d-chunk within row: d = 4*c4..4*c4+3
    const int half = lane >> 5;         // which of the pass's 2 rows

    // per-thread We chunk: rWe[j][h] = We[4*c4+j][h]
    float rWe[4][8];
    #pragma unroll
    for (int j = 0; j < 4; j++) {
        const float4* wp = (const float4*)(We + (4 * c4 + j) * 8);
        const float4 a = wp[0], bb = wp[1];
        rWe[j][0] = a.x; rWe[j][1] = a.y; rWe[j][2] = a.z; rWe[j][3] = a.w;
        rWe[j][4] = bb.x; rWe[j][5] = bb.y; rWe[j][6] = bb.z; rWe[j][7] = bb.w;
    }
    float be_r[8];
    #pragma unroll
    for (int h = 0; h < 8; h++) be_r[h] = be[h];

    // ---- Phase A: wave-private QK^T. thread (h=tid&7, kbase=tid>>3) covers
    // k = kbase+32i; kbase in [8w,8w+8) -> same wave as phase B's rows. ----
    {
        const int h = tid & 7;
        const int kbase = tid >> 3;
        const float4* qp = (const float4*)(Q + (size_t)bq * HIDDEN + h * HDIM);
        const float4 q0 = qp[0], q1 = qp[1], q2 = qp[2], q3 = qp[3];
        for (int i = 0; i < 16; i++) {
            const int k = kbase + 32 * i;
            const float4* kp = (const float4*)(K + (size_t)(b * NSEQ + k) * HIDDEN + h * HDIM);
            const float4 k0 = kp[0], k1 = kp[1], k2 = kp[2], k3 = kp[3];
            float acc = q0.x*k0.x + q0.y*k0.y + q0.z*k0.z + q0.w*k0.w;
            acc = fmaf(q1.x, k1.x, acc); acc = fmaf(q1.y, k1.y, acc);
            acc = fmaf(q1.z, k1.z, acc); acc = fmaf(q1.w, k1.w, acc);
            acc = fmaf(q2.x, k2.x, acc); acc = fmaf(q2.y, k2.y, acc);
            acc = fmaf(q2.z, k2.z, acc); acc = fmaf(q2.w, k2.w, acc);
            acc = fmaf(q3.x, k3.x, acc); acc = fmaf(q3.y, k3.y, acc);
            acc = fmaf(q3.z, k3.z, acc); acc = fmaf(q3.w, k3.w, acc);
            sS[k * SROW + h] = acc * 0.25f;   // 1/sqrt(16)
        }
    }
    // no barrier: phase B (same wave) syncs via lgkmcnt only

    // ---- Phase B: bias + mask, wave-private rows, zero barriers ----
    const int* mbase = mask + (size_t)bq * NSEQ;
    const float4* efb = (const float4*)(ef + (size_t)bq * NSEQ * HIDDEN);
    const int lbase = 256 * wv + lane;  // wave's 4KB chunk of each 16KB tile

    // pass P on float4 cp: rows rbase+2P+half, lane holds d = 4*c4..4*c4+3
    auto pass = [&](int rbase, int P, float4 cp) {
        const int r = rbase + 2 * P + half;
        const int mk = mbase[r];                 // broadcast L1 hit
        float pb[8];
        #pragma unroll
        for (int h = 0; h < 8; h++)
            pb[h] = fmaf(cp.w, rWe[3][h], fmaf(cp.z, rWe[2][h],
                     fmaf(cp.y, rWe[1][h], cp.x * rWe[0][h])));
        // fold 32 lanes: quad_perm -> quad sums everywhere; row_shr:4/8 is an
        // inclusive-scan tail -> 16-lane-row total lands in lanes (l&15)>=12;
        // xor16 adds the other 16-row -> full 32-lane sum at (l&31)==12 (and 28).
        #pragma unroll
        for (int h = 0; h < 8; h++) {
            float v = dppadd<QUAD_X2>(dppadd<QUAD_X1>(pb[h]));  // quad sum
            v = dppadd<ROW_SHR8>(dppadd<ROW_SHR4>(v));          // row total @ lanes 12..15
            pb[h] = swzadd_x16(v);                              // + other 16-row
        }
        if (c4 == 12) {         // lanes 12 and 44: one writer per row, full sum
            float* sp = &sS[r * SROW];
            const float2 o0 = *(float2*)(sp + 0);
            const float2 o1 = *(float2*)(sp + 2);
            const float2 o2 = *(float2*)(sp + 4);
            const float2 o3 = *(float2*)(sp + 6);
            float s0 = o0.x + pb[0] + be_r[0], s1 = o0.y + pb[1] + be_r[1];
            float s2 = o1.x + pb[2] + be_r[2], s3 = o1.y + pb[3] + be_r[3];
            float s4 = o2.x + pb[4] + be_r[4], s5 = o2.y + pb[5] + be_r[5];
            float s6 = o3.x + pb[6] + be_r[6], s7 = o3.y + pb[7] + be_r[7];
            s0 = mk ? s0 : NEGINF; s1 = mk ? s1 : NEGINF;
            s2 = mk ? s2 : NEGINF; s3 = mk ? s3 : NEGINF;
            s4 = mk ? s4 : NEGINF; s5 = mk ? s5 : NEGINF;
            s6 = mk ? s6 : NEGINF; s7 = mk ? s7 : NEGINF;
            *(float2*)(sp + 0) = make_float2(s0, s1);
            *(float2*)(sp + 2) = make_float2(s2, s3);
            *(float2*)(sp + 4) = make_float2(s4, s5);
            *(float2*)(sp + 6) = make_float2(s6, s7);
        }
    };

    float4 c0 = efb[lbase], c1 = efb[lbase + 64], c2 = efb[lbase + 128], c3 = efb[lbase + 192];
    for (int t = 0; t < 16; t++) {
        float4 n0, n1, n2, n3;
        if (t < 15) {
            const int o = (t + 1) * 1024 + lbase;
            n0 = efb[o]; n1 = efb[o + 64]; n2 = efb[o + 128]; n3 = efb[o + 192];
        }
        const int rbase = t * 32 + 8 * wv;
        pass(rbase, 0, c0);
        pass(rbase, 1, c1);
        pass(rbase, 2, c2);
        pass(rbase, 3, c3);
        if (t < 15) { c0 = n0; c1 = n1; c2 = n2; c3 = n3; }
    }
    __syncthreads();   // the ONE barrier before softmax

    // ---- Phase C: softmax per head (32 lanes per head, within-half shfl) ----
    {
        const int h = tid >> 5;
        const int j = tid & 31;
        float m = NEGINF;
        #pragma unroll
        for (int i = 0; i < 16; i++) m = fmaxf(m, sS[(j + 32 * i) * SROW + h]);
        #pragma unroll
        for (int off = 16; off >= 1; off >>= 1) m = fmaxf(m, __shfl_xor(m, off, 64));
        float sum = 0.f;
        #pragma unroll
        for (int i = 0; i < 16; i++) {
            const float s = sS[(j + 32 * i) * SROW + h];
            const float e = (s <= -1e29f) ? 0.f : __expf(s - m);
            sum += e;
            sS[(j + 32 * i) * SROW + h] = e;
        }
        #pragma unroll
        for (int off = 16; off >= 1; off >>= 1) sum += __shfl_xor(sum, off, 64);
        const float rinv = (sum > 0.f) ? 1.f / sum : 0.f;
        #pragma unroll
        for (int i = 0; i < 16; i++) sS[(j + 32 * i) * SROW + h] *= rinv;
    }
    __syncthreads();

    // ---- Phase D: out[d] = sum_k w[k][h] * V[b,k,d] (float4 over d) ----
    {
        const int d4 = tid & 31;            // d = 4*d4
        const int kg = tid >> 5;            // 64 k's per group
        const int h = d4 >> 2;
        const float4* v4 = (const float4*)(V + (size_t)b * NSEQ * HIDDEN) + d4;
        float4 acc = make_float4(0.f, 0.f, 0.f, 0.f);
        const int k0 = kg * 64;
        #pragma unroll 4
        for (int k = k0; k < k0 + 64; k++) {
            const float wgt = sS[k * SROW + h];
            const float4 vv = v4[(size_t)k * 32];
            acc.x = fmaf(wgt, vv.x, acc.x);
            acc.y = fmaf(wgt, vv.y, acc.y);
            acc.z = fmaf(wgt, vv.z, acc.z);
            acc.w = fmaf(wgt, vv.w, acc.w);
        }
        *(float4*)(&sPd[kg * 132 + d4 * 4]) = acc;
    }
    __syncthreads();
    if (tid < HIDDEN) {
        float s = 0.f;
        #pragma unroll
        for (int g = 0; g < 8; g++) s += sPd[g * 132 + tid];
        attn[bq * HIDDEN + tid] = s;
    }
}

// ---------------- Kernel 3: output projection ----------------
__global__ __launch_bounds__(128) void out_proj(
    const float* __restrict__ attn,
    const float* __restrict__ Wo, const float* __restrict__ bo,
    float* __restrict__ out)
{
    const int ROWS = 8;
    __shared__ float sX[ROWS][HIDDEN];
    const int row0 = blockIdx.x * ROWS;
    const int tid = threadIdx.x;

    const float4* src = (const float4*)(attn + row0 * HIDDEN);
    float4* dst = (float4*)(&sX[0][0]);
    #pragma unroll
    for (int i = 0; i < ROWS * HIDDEN / 4 / 128; i++)
        dst[tid + i * 128] = src[tid + i * 128];
    __syncthreads();

    float acc[ROWS];
    #pragma unroll
    for (int r = 0; r < ROWS; r++) acc[r] = 0.f;
    const int c = tid;
    for (int d = 0; d < HIDDEN; d++) {
        const float w = Wo[d * HIDDEN + c];
        #pragma unroll
        for (int r = 0; r < ROWS; r++)
            acc[r] = fmaf(sX[r][d], w, acc[r]);
    }
    const float bov = bo[c];
    #pragma unroll
    for (int r = 0; r < ROWS; r++)
        out[(row0 + r) * HIDDEN + c] = acc[r] + bov;
}

extern "C" void kernel_launch(void* const* d_in, const int* in_sizes, int n_in,
                              void* d_out, int out_size, void* d_ws, size_t ws_size,
                              hipStream_t stream) {
    const float* node = (const float*)d_in[0];
    const float* ef   = (const float*)d_in[1];
    const int*   mask = (const int*)d_in[2];
    const float* Wq = (const float*)d_in[3];
    const float* bq = (const float*)d_in[4];
    const float* Wk = (const float*)d_in[5];
    const float* bk = (const float*)d_in[6];
    const float* Wv = (const float*)d_in[7];
    const float* bv = (const float*)d_in[8];
    const float* We = (const float*)d_in[9];
    const float* be = (const float*)d_in[10];
    const float* Wo = (const float*)d_in[11];
    const float* bo = (const float*)d_in[12];
    float* out = (float*)d_out;

    const int ROWS_TOT = NBATCH * NSEQ;              // 2048
    const int RC = ROWS_TOT * HIDDEN;                // 262144 floats
    float* Q = (float*)d_ws;
    float* K = Q + RC;
    float* V = K + RC;
    float* attn = V + RC;

    qkv_proj<<<ROWS_TOT / 8, 128, 0, stream>>>(node, Wq, bq, Wk, bk, Wv, bv, Q, K, V);
    attn_fused<<<ROWS_TOT, 256, 0, stream>>>(ef, mask, We, be, Q, K, V, attn);
    out_proj<<<ROWS_TOT / 8, 128, 0, stream>>>(attn, Wo, bo, out);
}

// Round 6
// 193.413 us; speedup vs baseline: 1.1805x; 1.1805x over previous
//
#include <hip/hip_runtime.h>
#include <math.h>

#define HIDDEN 128
#define HEADS 8
#define HDIM 16
#define NSEQ 512
#define NBATCH 4
#define SROW 10         // sS row stride, [k][h] layout: all phases <=2-way banks
#define NEGINF (-1e30f)

// v += lane-permuted v. DPP = VALU; ds_swizzle = LDS pipe (used once/head).
template <int CTRL>
__device__ __forceinline__ float dppadd(float v) {
    int s = __builtin_amdgcn_update_dpp(0, __float_as_int(v), CTRL, 0xF, 0xF, true);
    return v + __int_as_float(s);
}
__device__ __forceinline__ float swzadd_x16(float v) {
    int s = __builtin_amdgcn_ds_swizzle(__float_as_int(v), 0x401F);  // xor lane^16
    return v + __int_as_float(s);
}
#define QUAD_X1 0xB1    // quad_perm [1,0,3,2]
#define QUAD_X2 0x4E    // quad_perm [2,3,0,1]
#define ROW_SHR4 0x114
#define ROW_SHR8 0x118

// ---------------- Kernel 1: fused Q/K/V projection ----------------
__global__ __launch_bounds__(128) void qkv_proj(
    const float* __restrict__ node,
    const float* __restrict__ Wq, const float* __restrict__ bq,
    const float* __restrict__ Wk, const float* __restrict__ bk,
    const float* __restrict__ Wv, const float* __restrict__ bv,
    float* __restrict__ Q, float* __restrict__ K, float* __restrict__ V)
{
    const int ROWS = 8;
    __shared__ float sX[ROWS][HIDDEN];
    const int row0 = blockIdx.x * ROWS;
    const int tid = threadIdx.x;

    const float4* src = (const float4*)(node + row0 * HIDDEN);
    float4* dst = (float4*)(&sX[0][0]);
    #pragma unroll
    for (int i = 0; i < ROWS * HIDDEN / 4 / 128; i++)
        dst[tid + i * 128] = src[tid + i * 128];
    __syncthreads();

    float accQ[ROWS], accK[ROWS], accV[ROWS];
    #pragma unroll
    for (int r = 0; r < ROWS; r++) { accQ[r] = 0.f; accK[r] = 0.f; accV[r] = 0.f; }
    const int c = tid;
    for (int d = 0; d < HIDDEN; d++) {
        const float wq = Wq[d * HIDDEN + c];
        const float wk = Wk[d * HIDDEN + c];
        const float wv = Wv[d * HIDDEN + c];
        #pragma unroll
        for (int r = 0; r < ROWS; r++) {
            const float x = sX[r][d];
            accQ[r] = fmaf(x, wq, accQ[r]);
            accK[r] = fmaf(x, wk, accK[r]);
            accV[r] = fmaf(x, wv, accV[r]);
        }
    }
    const float bqv = bq[c], bkv = bk[c], bvv = bv[c];
    #pragma unroll
    for (int r = 0; r < ROWS; r++) {
        const int off = (row0 + r) * HIDDEN + c;
        Q[off] = accQ[r] + bqv;
        K[off] = accK[r] + bkv;
        V[off] = accV[r] + bvv;
    }
}

// ---------------- Kernel 2: fused attention, barrier-free k-loop ----------------
// sS is [k][h] (stride SROW). Wave w owns score rows with (k&31)>>3 == w in
// phase A (QK) and phase B (bias+mask RMW): no cross-wave deps, no barriers
// until softmax. Phase B: 2 rows/pass (row = lane>>5), DPP scan fold + ONE
// ds_swizzle per head; 16 parallel 1-float RMW writers (lanes (l&15)>=12).
__global__ __launch_bounds__(256, 3) void attn_fused(
    const float* __restrict__ ef,     // [B][N][N][HIDDEN]
    const int*   __restrict__ mask,   // [B][N][N]
    const float* __restrict__ We,     // [HIDDEN][HEADS]
    const float* __restrict__ be,     // [HEADS]
    const float* __restrict__ Q, const float* __restrict__ K,
    const float* __restrict__ V,
    float* __restrict__ attn)         // [B*N][HIDDEN]
{
    __shared__ float sS[NSEQ * SROW];   // scores -> weights, [k][h]
    __shared__ float sPd[8 * 132];      // PV partials

    const int bq = blockIdx.x;          // b*512 + q
    const int b  = bq >> 9;
    const int tid = threadIdx.x;
    const int wvid = tid >> 6;          // wave id 0..3
    const int lane = tid & 63;
    const int dgrp = lane & 31;         // d-chunk: d = 4*dgrp .. 4*dgrp+3
    const int rsel = lane >> 5;         // which of the pass's 2 rows
    const bool wr = (lane & 15) >= 12;  // writer lanes: full row sums live here
    const int hsel = (((lane & 15) - 12) & 3) | (((lane >> 4) & 1) << 2); // 0..7

    // per-thread We chunk: rWe[j][h] = We[4*dgrp+j][h]
    float rWe[4][8];
    #pragma unroll
    for (int j = 0; j < 4; j++) {
        const float4* wp = (const float4*)(We + (4 * dgrp + j) * 8);
        const float4 a = wp[0], bb = wp[1];
        rWe[j][0] = a.x; rWe[j][1] = a.y; rWe[j][2] = a.z; rWe[j][3] = a.w;
        rWe[j][4] = bb.x; rWe[j][5] = bb.y; rWe[j][6] = bb.z; rWe[j][7] = bb.w;
    }
    const float be_sel = be[hsel];      // writer's head bias

    // ---- Phase A: wave-private QK^T (kbase = tid>>3 in [8w,8w+8)) ----
    {
        const int h = tid & 7;
        const int kbase = tid >> 3;
        const float4* qp = (const float4*)(Q + (size_t)bq * HIDDEN + h * HDIM);
        const float4 q0 = qp[0], q1 = qp[1], q2 = qp[2], q3 = qp[3];
        for (int i = 0; i < 16; i++) {
            const int k = kbase + 32 * i;
            const float4* kp = (const float4*)(K + (size_t)(b * NSEQ + k) * HIDDEN + h * HDIM);
            const float4 k0 = kp[0], k1 = kp[1], k2 = kp[2], k3 = kp[3];
            float acc = q0.x*k0.x + q0.y*k0.y + q0.z*k0.z + q0.w*k0.w;
            acc = fmaf(q1.x, k1.x, acc); acc = fmaf(q1.y, k1.y, acc);
            acc = fmaf(q1.z, k1.z, acc); acc = fmaf(q1.w, k1.w, acc);
            acc = fmaf(q2.x, k2.x, acc); acc = fmaf(q2.y, k2.y, acc);
            acc = fmaf(q2.z, k2.z, acc); acc = fmaf(q2.w, k2.w, acc);
            acc = fmaf(q3.x, k3.x, acc); acc = fmaf(q3.y, k3.y, acc);
            acc = fmaf(q3.z, k3.z, acc); acc = fmaf(q3.w, k3.w, acc);
            sS[k * SROW + h] = acc * 0.25f;   // 1/sqrt(16)
        }
    }
    // no barrier: phase B (same wave) syncs via lgkmcnt only

    // ---- Phase B: bias + mask, wave-private rows, zero barriers ----
    const int* mbase = mask + (size_t)bq * NSEQ;
    const float4* efb = (const float4*)(ef + (size_t)bq * NSEQ * HIDDEN);

    // pass: this lane's row r, its float4 d-chunk cp, its row's mask mk
    auto pass = [&](int r, float4 cp, int mk) {
        float pb[8];
        #pragma unroll
        for (int h = 0; h < 8; h++)
            pb[h] = fmaf(cp.w, rWe[3][h], fmaf(cp.z, rWe[2][h],
                     fmaf(cp.y, rWe[1][h], cp.x * rWe[0][h])));
        #pragma unroll
        for (int h = 0; h < 8; h++) {
            float v = dppadd<QUAD_X2>(dppadd<QUAD_X1>(pb[h]));  // quad sums
            v = dppadd<ROW_SHR8>(dppadd<ROW_SHR4>(v));          // 16-lane totals @ (l&15)>=12
            pb[h] = swzadd_x16(v);                              // + other 16-group (1 LDS op)
        }
        // writer lanes (l&15)>=12 of both halves: static-select own head's sum
        float val = pb[0];
        val = (hsel == 1) ? pb[1] : val;
        val = (hsel == 2) ? pb[2] : val;
        val = (hsel == 3) ? pb[3] : val;
        val = (hsel == 4) ? pb[4] : val;
        val = (hsel == 5) ? pb[5] : val;
        val = (hsel == 6) ? pb[6] : val;
        val = (hsel == 7) ? pb[7] : val;
        if (wr) {
            float* sp = &sS[r * SROW + hsel];
            const float s = *sp;
            *sp = mk ? (s + val + be_sel) : NEGINF;
        }
    };

    // tile t covers rows rbase..rbase+7 (this wave); pass P rows rbase+2P+rsel
    const int rb0 = 8 * wvid;
    float4 c0 = efb[(rb0 + 0 + rsel) * 32 + dgrp];
    float4 c1 = efb[(rb0 + 2 + rsel) * 32 + dgrp];
    float4 c2 = efb[(rb0 + 4 + rsel) * 32 + dgrp];
    float4 c3 = efb[(rb0 + 6 + rsel) * 32 + dgrp];
    int mk0 = mbase[rb0 + 0 + rsel];
    int mk1 = mbase[rb0 + 2 + rsel];
    int mk2 = mbase[rb0 + 4 + rsel];
    int mk3 = mbase[rb0 + 6 + rsel];

    for (int t = 0; t < 16; t++) {
        float4 n0, n1, n2, n3; int nm0 = 0, nm1 = 0, nm2 = 0, nm3 = 0;
        if (t < 15) {
            const int nb = (t + 1) * 32 + rb0;
            n0 = efb[(nb + 0 + rsel) * 32 + dgrp];
            n1 = efb[(nb + 2 + rsel) * 32 + dgrp];
            n2 = efb[(nb + 4 + rsel) * 32 + dgrp];
            n3 = efb[(nb + 6 + rsel) * 32 + dgrp];
            nm0 = mbase[nb + 0 + rsel]; nm1 = mbase[nb + 2 + rsel];
            nm2 = mbase[nb + 4 + rsel]; nm3 = mbase[nb + 6 + rsel];
        }
        const int rbase = t * 32 + rb0;
        pass(rbase + 0 + rsel, c0, mk0);
        pass(rbase + 2 + rsel, c1, mk1);
        pass(rbase + 4 + rsel, c2, mk2);
        pass(rbase + 6 + rsel, c3, mk3);
        if (t < 15) {
            c0 = n0; c1 = n1; c2 = n2; c3 = n3;
            mk0 = nm0; mk1 = nm1; mk2 = nm2; mk3 = nm3;
        }
    }
    __syncthreads();   // the ONE barrier before softmax

    // ---- Phase C: softmax per head (32 lanes per head) ----
    {
        const int h = tid >> 5;
        const int j = tid & 31;
        float m = NEGINF;
        #pragma unroll
        for (int i = 0; i < 16; i++) m = fmaxf(m, sS[(j + 32 * i) * SROW + h]);
        #pragma unroll
        for (int off = 16; off >= 1; off >>= 1) m = fmaxf(m, __shfl_xor(m, off, 64));
        float sum = 0.f;
        #pragma unroll
        for (int i = 0; i < 16; i++) {
            const float s = sS[(j + 32 * i) * SROW + h];
            const float e = (s <= -1e29f) ? 0.f : __expf(s - m);
            sum += e;
            sS[(j + 32 * i) * SROW + h] = e;
        }
        #pragma unroll
        for (int off = 16; off >= 1; off >>= 1) sum += __shfl_xor(sum, off, 64);
        const float rinv = (sum > 0.f) ? 1.f / sum : 0.f;
        #pragma unroll
        for (int i = 0; i < 16; i++) sS[(j + 32 * i) * SROW + h] *= rinv;
    }
    __syncthreads();

    // ---- Phase D: out[d] = sum_k w[k][h] * V[b,k,d] (float4 over d) ----
    {
        const int d4 = tid & 31;            // d = 4*d4
        const int kg = tid >> 5;            // 64 k's per group
        const int h = d4 >> 2;
        const float4* v4 = (const float4*)(V + (size_t)b * NSEQ * HIDDEN) + d4;
        float4 acc = make_float4(0.f, 0.f, 0.f, 0.f);
        const int k0 = kg * 64;
        #pragma unroll 4
        for (int k = k0; k < k0 + 64; k++) {
            const float wgt = sS[k * SROW + h];
            const float4 vv = v4[(size_t)k * 32];
            acc.x = fmaf(wgt, vv.x, acc.x);
            acc.y = fmaf(wgt, vv.y, acc.y);
            acc.z = fmaf(wgt, vv.z, acc.z);
            acc.w = fmaf(wgt, vv.w, acc.w);
        }
        *(float4*)(&sPd[kg * 132 + d4 * 4]) = acc;
    }
    __syncthreads();
    if (tid < HIDDEN) {
        float s = 0.f;
        #pragma unroll
        for (int g = 0; g < 8; g++) s += sPd[g * 132 + tid];
        attn[bq * HIDDEN + tid] = s;
    }
}

// ---------------- Kernel 3: output projection ----------------
__global__ __launch_bounds__(128) void out_proj(
    const float* __restrict__ attn,
    const float* __restrict__ Wo, const float* __restrict__ bo,
    float* __restrict__ out)
{
    const int ROWS = 8;
    __shared__ float sX[ROWS][HIDDEN];
    const int row0 = blockIdx.x * ROWS;
    const int tid = threadIdx.x;

    const float4* src = (const float4*)(attn + row0 * HIDDEN);
    float4* dst = (float4*)(&sX[0][0]);
    #pragma unroll
    for (int i = 0; i < ROWS * HIDDEN / 4 / 128; i++)
        dst[tid + i * 128] = src[tid + i * 128];
    __syncthreads();

    float acc[ROWS];
    #pragma unroll
    for (int r = 0; r < ROWS; r++) acc[r] = 0.f;
    const int c = tid;
    for (int d = 0; d < HIDDEN; d++) {
        const float w = Wo[d * HIDDEN + c];
        #pragma unroll
        for (int r = 0; r < ROWS; r++)
            acc[r] = fmaf(sX[r][d], w, acc[r]);
    }
    const float bov = bo[c];
    #pragma unroll
    for (int r = 0; r < ROWS; r++)
        out[(row0 + r) * HIDDEN + c] = acc[r] + bov;
}

extern "C" void kernel_launch(void* const* d_in, const int* in_sizes, int n_in,
                              void* d_out, int out_size, void* d_ws, size_t ws_size,
                              hipStream_t stream) {
    const float* node = (const float*)d_in[0];
    const float* ef   = (const float*)d_in[1];
    const int*   mask = (const int*)d_in[2];
    const float* Wq = (const float*)d_in[3];
    const float* bq = (const float*)d_in[4];
    const float* Wk = (const float*)d_in[5];
    const float* bk = (const float*)d_in[6];
    const float* Wv = (const float*)d_in[7];
    const float* bv = (const float*)d_in[8];
    const float* We = (const float*)d_in[9];
    const float* be = (const float*)d_in[10];
    const float* Wo = (const float*)d_in[11];
    const float* bo = (const float*)d_in[12];
    float* out = (float*)d_out;

    const int ROWS_TOT = NBATCH * NSEQ;              // 2048
    const int RC = ROWS_TOT * HIDDEN;                // 262144 floats
    float* Q = (float*)d_ws;
    float* K = Q + RC;
    float* V = K + RC;
    float* attn = V + RC;

    qkv_proj<<<ROWS_TOT / 8, 128, 0, stream>>>(node, Wq, bq, Wk, bk, Wv, bv, Q, K, V);
    attn_fused<<<ROWS_TOT, 256, 0, stream>>>(ef, mask, We, be, Q, K, V, attn);
    out_proj<<<ROWS_TOT / 8, 128, 0, stream>>>(attn, Wo, bo, out);
}